// Round 4
// baseline (250.711 us; speedup 1.0000x reference)
//
#include <hip/hip_runtime.h>

// Problem: S=8192, K=1024, O=4096
// out_q[s,o] = clip(round(int8dot(x[s,:], w[o,:]) * sx*sw/sy[s]), -128, 127)
// d_out = [ out_q as float (S*O) | scale_y (S) ]

#define S_DIM 8192
#define K_DIM 1024
#define O_DIM 4096
#define BM 128
#define BN 128
#define BK 64
#define NITER (K_DIM / BK)

using i32x4 = __attribute__((ext_vector_type(4))) int;

__device__ __forceinline__ void load_lds16(const void* g, void* l) {
  __builtin_amdgcn_global_load_lds(
      (const __attribute__((address_space(1))) void*)g,
      (__attribute__((address_space(3))) void*)l, 16, 0, 0);
}

// ---------------- pack: int32 -> int8 for x and w, plus scale_y passthrough ----
__global__ void pack_kernel(const int* __restrict__ xi, const int* __restrict__ wi,
                            const float* __restrict__ sy,
                            unsigned int* __restrict__ xq, unsigned int* __restrict__ wq,
                            float* __restrict__ out_sy) {
  const int idx = blockIdx.x * blockDim.x + threadIdx.x;
  const int nx = S_DIM * K_DIM / 4;  // 2M packed words
  const int nw = O_DIM * K_DIM / 4;  // 1M packed words
  if (idx < nx) {
    int4 v = ((const int4*)xi)[idx];
    unsigned int p = (v.x & 0xff) | ((v.y & 0xff) << 8) |
                     ((v.z & 0xff) << 16) | ((unsigned)(v.w & 0xff) << 24);
    xq[idx] = p;
  } else if (idx < nx + nw) {
    const int j = idx - nx;
    int4 v = ((const int4*)wi)[j];
    unsigned int p = (v.x & 0xff) | ((v.y & 0xff) << 8) |
                     ((v.z & 0xff) << 16) | ((unsigned)(v.w & 0xff) << 24);
    wq[j] = p;
  }
  if (idx < S_DIM) out_sy[idx] = sy[idx];
}

// ---------------- int8 MFMA GEMM, dbuf + 5 blocks/CU + XCD swizzle ------------
// Block: 256 threads = 4 waves in 2x2; wave owns 64x64 = 4x4 grid of
// 16x16x64 i8 MFMA tiles. Double-buffered LDS (2 x 16 KB), one barrier/iter.
// launch_bounds(256,5): 5 waves/EU -> 5 blocks/CU (LDS limit is also 5 at
// 32 KB/block). Inner loop keeps only one A-fragment live (acc 64 + bf 16 +
// af 4 + addr ~= 95 VGPR < 102 cap) to avoid spills.
// XCD swizzle: linear block l -> xcd = l&7 owns a 4-col-tile stripe (512 KB
// of B stays hot in that XCD's 4 MB L2; A-tile reused 4x back-to-back).
__global__ __launch_bounds__(256, 5) void gemm_i8_kernel(
    const signed char* __restrict__ A,   // packed x [S,K] int8
    const signed char* __restrict__ B,   // packed w [O,K] int8
    const float* __restrict__ sx, const float* __restrict__ sw,
    const float* __restrict__ sy, float* __restrict__ out) {
  __shared__ __align__(16) signed char As[2][BM * BK];
  __shared__ __align__(16) signed char Bs[2][BN * BK];

  const int tid = threadIdx.x;
  const int wave = tid >> 6;
  const int lane = tid & 63;
  const int wm = wave >> 1;  // 0..1: wave row in block
  const int wn = wave & 1;   // 0..1: wave col in block

  // XCD-aware swizzle over flat grid of 2048 blocks -> (col tile bx, row tile by)
  const int l = blockIdx.x;
  const int xcd = l & 7;
  const int i = l >> 3;                 // 0..255 within XCD
  const int bx = xcd * 4 + (i & 3);     // 0..31 col tile (stripe per XCD)
  const int by = i >> 2;                // 0..63 row tile
  const int rowBase = by * BM;
  const int colBase = bx * BN;

  // Staging map: round r (r=0,1) covers block rows [r*64, r*64+64):
  // lane -> row = r*64 + wave*16 + lane/4, col = (lane%4)*16.
  // LDS byte = r*4096 + wave*1024 + lane*16 (wave-uniform base + lane*16).
  const int sRow = wave * 16 + (lane >> 2);
  const int sCol = (lane & 3) * 16;
  const signed char* gA = A + (size_t)(rowBase + sRow) * K_DIM + sCol;
  const signed char* gB = B + (size_t)(colBase + sRow) * K_DIM + sCol;

  i32x4 acc[4][4] = {};

  const int fr = lane & 15;          // row within 16x16 fragment
  const int fq = (lane >> 4) * 16;   // K-chunk byte offset for this quad

  // Prologue: stage tile 0 into buffer 0.
  {
    signed char* lA = As[0] + wave * 1024;
    signed char* lB = Bs[0] + wave * 1024;
    load_lds16(gA, lA);
    load_lds16(gA + (size_t)64 * K_DIM, lA + 4096);
    load_lds16(gB, lB);
    load_lds16(gB + (size_t)64 * K_DIM, lB + 4096);
  }

  for (int it = 0; it < NITER; ++it) {
    __syncthreads();  // drains vmcnt of stage issued last iter; buffer ready

    if (it + 1 < NITER) {  // async-stage next tile into the other buffer
      const int nb = (it + 1) & 1;
      const int k0 = (it + 1) * BK;
      signed char* lA = As[nb] + wave * 1024;
      signed char* lB = Bs[nb] + wave * 1024;
      load_lds16(gA + k0, lA);
      load_lds16(gA + (size_t)64 * K_DIM + k0, lA + 4096);
      load_lds16(gB + k0, lB);
      load_lds16(gB + (size_t)64 * K_DIM + k0, lB + 4096);
    }

    const signed char* curA = As[it & 1];
    const signed char* curB = Bs[it & 1];
    i32x4 bf[4];
#pragma unroll
    for (int ni = 0; ni < 4; ++ni)
      bf[ni] = *(const i32x4*)(curB + (wn * 64 + ni * 16 + fr) * BK + fq);

#pragma unroll
    for (int mi = 0; mi < 4; ++mi) {
      i32x4 af = *(const i32x4*)(curA + (wm * 64 + mi * 16 + fr) * BK + fq);
#pragma unroll
      for (int ni = 0; ni < 4; ++ni)
        acc[mi][ni] =
            __builtin_amdgcn_mfma_i32_16x16x64_i8(af, bf[ni], acc[mi][ni], 0, 0, 0);
    }
  }

  // Epilogue. C/D layout: col = lane&15, row = (lane>>4)*4 + reg.
  const float sxw = sx[0] * sw[0];
  const int quad = lane >> 4;
#pragma unroll
  for (int mi = 0; mi < 4; ++mi) {
#pragma unroll
    for (int r = 0; r < 4; ++r) {
      const int s = rowBase + wm * 64 + mi * 16 + quad * 4 + r;
      const float rs = sxw / sy[s];
      float* orow = out + (size_t)s * O_DIM + colBase + wn * 64 + fr;
#pragma unroll
      for (int ni = 0; ni < 4; ++ni) {
        float f = rintf((float)acc[mi][ni][r] * rs);
        f = fminf(127.0f, fmaxf(-128.0f, f));
        orow[ni * 16] = f;
      }
    }
  }
}

extern "C" void kernel_launch(void* const* d_in, const int* in_sizes, int n_in,
                              void* d_out, int out_size, void* d_ws, size_t ws_size,
                              hipStream_t stream) {
  const int* x = (const int*)d_in[0];        // [S,K] int8 values as int32
  const int* w = (const int*)d_in[1];        // [O,K] int8 values as int32
  const float* sx = (const float*)d_in[2];
  const float* sw = (const float*)d_in[3];
  const float* sy = (const float*)d_in[4];   // [S]
  float* out = (float*)d_out;

  unsigned int* xq = (unsigned int*)d_ws;                         // 8 MB
  unsigned int* wq = xq + (size_t)S_DIM * K_DIM / 4;              // 4 MB

  const int total = S_DIM * K_DIM / 4 + O_DIM * K_DIM / 4;  // 3M threads
  pack_kernel<<<(total + 255) / 256, 256, 0, stream>>>(
      x, w, sy, xq, wq, out + (size_t)S_DIM * O_DIM);

  gemm_i8_kernel<<<dim3(2048), 256, 0, stream>>>(
      (const signed char*)xq, (const signed char*)wq, sx, sw, sy, out);
}

// Round 5
// 205.314 us; speedup vs baseline: 1.2211x; 1.2211x over previous
//
#include <hip/hip_runtime.h>

// Problem: S=8192, K=1024, O=4096
// out_q[s,o] = clip(round(int8dot(x[s,:], w[o,:]) * sx*sw/sy[s]), -128, 127)
// d_out = [ out_q as float (S*O) | scale_y (S) ]

#define S_DIM 8192
#define K_DIM 1024
#define O_DIM 4096
#define BM 128
#define BN 128
#define BK 64
#define NITER (K_DIM / BK)

using i32x4 = __attribute__((ext_vector_type(4))) int;

__device__ __forceinline__ void load_lds16(const void* g, void* l) {
  __builtin_amdgcn_global_load_lds(
      (const __attribute__((address_space(1))) void*)g,
      (__attribute__((address_space(3))) void*)l, 16, 0, 0);
}

// ---------------- pack: int32 -> int8 for x and w, plus scale_y passthrough ----
__global__ void pack_kernel(const int* __restrict__ xi, const int* __restrict__ wi,
                            const float* __restrict__ sy,
                            unsigned int* __restrict__ xq, unsigned int* __restrict__ wq,
                            float* __restrict__ out_sy) {
  const int idx = blockIdx.x * blockDim.x + threadIdx.x;
  const int nx = S_DIM * K_DIM / 4;  // 2M packed words
  const int nw = O_DIM * K_DIM / 4;  // 1M packed words
  if (idx < nx) {
    int4 v = ((const int4*)xi)[idx];
    unsigned int p = (v.x & 0xff) | ((v.y & 0xff) << 8) |
                     ((v.z & 0xff) << 16) | ((unsigned)(v.w & 0xff) << 24);
    xq[idx] = p;
  } else if (idx < nx + nw) {
    const int j = idx - nx;
    int4 v = ((const int4*)wi)[j];
    unsigned int p = (v.x & 0xff) | ((v.y & 0xff) << 8) |
                     ((v.z & 0xff) << 16) | ((unsigned)(v.w & 0xff) << 24);
    wq[j] = p;
  }
  if (idx < S_DIM) out_sy[idx] = sy[idx];
}

// ---------------- int8 MFMA GEMM, dbuf + bank-conflict-free LDS swizzle -------
// Block: 256 threads = 4 waves in 2x2; wave owns 64x64 = 4x4 grid of
// 16x16x64 i8 MFMA tiles. Double-buffered LDS (2 x 16 KB), one barrier/iter.
//
// LDS swizzle: tile row r's 64B is stored as 4 chunks of 16B where slot c
// holds global K-chunk (c ^ (r&3)). Stager implements it by permuting each
// lane's GLOBAL source column (LDS dest must stay base + lane*16 for
// global_load_lds). Reader: chunk q of row r is at slot q ^ (r&3), making
// each 32-lane ds_read_b128 phase cover all 32 banks (was: half the banks,
// 4 extra cyc/read = 4.2M conflict cycles per dispatch in R4's counters).
__global__ __launch_bounds__(256, 4) void gemm_i8_kernel(
    const signed char* __restrict__ A,   // packed x [S,K] int8
    const signed char* __restrict__ B,   // packed w [O,K] int8
    const float* __restrict__ sx, const float* __restrict__ sw,
    const float* __restrict__ sy, float* __restrict__ out) {
  __shared__ __align__(16) signed char As[2][BM * BK];
  __shared__ __align__(16) signed char Bs[2][BN * BK];

  const int tid = threadIdx.x;
  const int wave = tid >> 6;
  const int lane = tid & 63;
  const int wm = wave >> 1;  // 0..1: wave row in block
  const int wn = wave & 1;   // 0..1: wave col in block
  const int rowBase = blockIdx.x * BM;   // x-fast over S keeps B L2-resident
  const int colBase = blockIdx.y * BN;

  // Staging map: round r (r=0,1) covers block rows [r*64, r*64+64):
  // lane -> row = r*64 + wave*16 + lane/4; global col chunk = (lane&3) ^ (row&3)
  // (XOR swizzle); LDS byte = r*4096 + wave*1024 + lane*16 (uniform + lane*16).
  const int sRow = wave * 16 + (lane >> 2);
  const int sCol = (((lane & 3) ^ ((lane >> 2) & 3))) * 16;  // swizzled source
  const signed char* gA = A + (size_t)(rowBase + sRow) * K_DIM + sCol;
  const signed char* gB = B + (size_t)(colBase + sRow) * K_DIM + sCol;

  i32x4 acc[4][4] = {};

  const int fr = lane & 15;                          // row within 16x16 fragment
  const int fq = (((lane >> 4) ^ (fr & 3)) & 3) * 16;  // swizzled LDS chunk slot

  // Prologue: stage tile 0 into buffer 0.
  {
    signed char* lA = As[0] + wave * 1024;
    signed char* lB = Bs[0] + wave * 1024;
    load_lds16(gA, lA);
    load_lds16(gA + (size_t)64 * K_DIM, lA + 4096);
    load_lds16(gB, lB);
    load_lds16(gB + (size_t)64 * K_DIM, lB + 4096);
  }

  for (int it = 0; it < NITER; ++it) {
    __syncthreads();  // drains vmcnt of stage issued last iter; buffer ready

    if (it + 1 < NITER) {  // async-stage next tile into the other buffer
      const int nb = (it + 1) & 1;
      const int k0 = (it + 1) * BK;
      signed char* lA = As[nb] + wave * 1024;
      signed char* lB = Bs[nb] + wave * 1024;
      load_lds16(gA + k0, lA);
      load_lds16(gA + (size_t)64 * K_DIM + k0, lA + 4096);
      load_lds16(gB + k0, lB);
      load_lds16(gB + (size_t)64 * K_DIM + k0, lB + 4096);
    }

    const signed char* curA = As[it & 1];
    const signed char* curB = Bs[it & 1];
    i32x4 bf[4];
#pragma unroll
    for (int ni = 0; ni < 4; ++ni)
      bf[ni] = *(const i32x4*)(curB + (wn * 64 + ni * 16 + fr) * BK + fq);

#pragma unroll
    for (int mi = 0; mi < 4; ++mi) {
      i32x4 af = *(const i32x4*)(curA + (wm * 64 + mi * 16 + fr) * BK + fq);
#pragma unroll
      for (int ni = 0; ni < 4; ++ni)
        acc[mi][ni] =
            __builtin_amdgcn_mfma_i32_16x16x64_i8(af, bf[ni], acc[mi][ni], 0, 0, 0);
    }
  }

  // Epilogue. C/D layout: col = lane&15, row = (lane>>4)*4 + reg.
  const float sxw = sx[0] * sw[0];
  const int quad = lane >> 4;
#pragma unroll
  for (int mi = 0; mi < 4; ++mi) {
#pragma unroll
    for (int r = 0; r < 4; ++r) {
      const int s = rowBase + wm * 64 + mi * 16 + quad * 4 + r;
      const float rs = sxw / sy[s];
      float* orow = out + (size_t)s * O_DIM + colBase + wn * 64 + fr;
#pragma unroll
      for (int ni = 0; ni < 4; ++ni) {
        float f = rintf((float)acc[mi][ni][r] * rs);
        f = fminf(127.0f, fmaxf(-128.0f, f));
        orow[ni * 16] = f;
      }
    }
  }
}

extern "C" void kernel_launch(void* const* d_in, const int* in_sizes, int n_in,
                              void* d_out, int out_size, void* d_ws, size_t ws_size,
                              hipStream_t stream) {
  const int* x = (const int*)d_in[0];        // [S,K] int8 values as int32
  const int* w = (const int*)d_in[1];        // [O,K] int8 values as int32
  const float* sx = (const float*)d_in[2];
  const float* sw = (const float*)d_in[3];
  const float* sy = (const float*)d_in[4];   // [S]
  float* out = (float*)d_out;

  unsigned int* xq = (unsigned int*)d_ws;                         // 8 MB
  unsigned int* wq = xq + (size_t)S_DIM * K_DIM / 4;              // 4 MB

  const int total = S_DIM * K_DIM / 4 + O_DIM * K_DIM / 4;  // 3M threads
  pack_kernel<<<(total + 255) / 256, 256, 0, stream>>>(
      x, w, sy, xq, wq, out + (size_t)S_DIM * O_DIM);

  dim3 grid(S_DIM / BM, O_DIM / BN);  // (64, 32), row tiles fast
  gemm_i8_kernel<<<grid, 256, 0, stream>>>(
      (const signed char*)xq, (const signed char*)wq, sx, sw, sy, out);
}

// Round 6
// 200.932 us; speedup vs baseline: 1.2477x; 1.0218x over previous
//
#include <hip/hip_runtime.h>

// Problem: S=8192, K=1024, O=4096
// out_q[s,o] = clip(round(int8dot(x[s,:], w[o,:]) * sx*sw/sy[s]), -128, 127)
// d_out = [ out_q as float (S*O) | scale_y (S) ]

#define S_DIM 8192
#define K_DIM 1024
#define O_DIM 4096
#define BM 128
#define BN 128
#define BK 64
#define NITER (K_DIM / BK)
#define TILE_BYTES (BM * BK)  // 8192 B staging tile

using i32x4 = __attribute__((ext_vector_type(4))) int;

__device__ __forceinline__ void load_lds16(const void* g, void* l) {
  __builtin_amdgcn_global_load_lds(
      (const __attribute__((address_space(1))) void*)g,
      (__attribute__((address_space(3))) void*)l, 16, 0, 0);
}

// ---------------- pack: int32 -> int8 into STAGING-TILE layout ----------------
// Output layout (A): tile t = band*16 + ktile (band = s/128, ktile = k/64),
// 8 KB each. Within tile: byte r*64 + cs*16 holds chunk (cs ^ (r&3)) of row
// band*128+r  (bank-swizzle baked in, identical LDS image to R5's stager).
// One thread per 16 B output chunk: reads 16 int32 (64 B), writes uint4.
// This makes gemm staging fully CONTIGUOUS: 4 cache lines per
// global_load_lds_dwordx4 instead of 16 (R1-R5's hidden request-pipe wall).
__global__ void pack_kernel(const int* __restrict__ xi, const int* __restrict__ wi,
                            const float* __restrict__ sy,
                            uint4* __restrict__ ap, uint4* __restrict__ bp,
                            float* __restrict__ out_sy) {
  const int tid = blockIdx.x * blockDim.x + threadIdx.x;
  const int nA = S_DIM * K_DIM / 16;  // 512K chunks
  const int nB = O_DIM * K_DIM / 16;  // 256K chunks

  const int* src;
  uint4* dst;
  int j;
  if (tid < nA) {
    src = xi; dst = ap; j = tid;
  } else if (tid < nA + nB) {
    src = wi; dst = bp; j = tid - nA;
  } else {
    return;
  }
  const int t = j >> 9;          // tile index (512 chunks/tile)
  const int idx = j & 511;
  const int r = idx >> 2;        // row within tile 0..127
  const int cs = idx & 3;        // chunk slot
  const int c = cs ^ (r & 3);    // global chunk (swizzle)
  const int band = t >> 4;       // 16 ktiles per band
  const int kt = t & 15;
  const int row = band * 128 + r;
  // int4 index base: (row*1024 + kt*64 + c*16) / 4
  const int4* s4 = (const int4*)src + row * 256 + kt * 16 + c * 4;
  int4 v0 = s4[0], v1 = s4[1], v2 = s4[2], v3 = s4[3];
  uint4 o;
  o.x = (v0.x & 0xff) | ((v0.y & 0xff) << 8) | ((v0.z & 0xff) << 16) | (((unsigned)v0.w & 0xff) << 24);
  o.y = (v1.x & 0xff) | ((v1.y & 0xff) << 8) | ((v1.z & 0xff) << 16) | (((unsigned)v1.w & 0xff) << 24);
  o.z = (v2.x & 0xff) | ((v2.y & 0xff) << 8) | ((v2.z & 0xff) << 16) | (((unsigned)v2.w & 0xff) << 24);
  o.w = (v3.x & 0xff) | ((v3.y & 0xff) << 8) | ((v3.z & 0xff) << 16) | (((unsigned)v3.w & 0xff) << 24);
  dst[j] = o;
  if (tid < S_DIM) out_sy[tid] = sy[tid];
}

// ---------------- int8 MFMA GEMM, contiguous tiled staging --------------------
// Block: 256 threads = 4 waves in 2x2; wave owns 64x64 = 4x4 grid of
// 16x16x64 i8 MFMA tiles. Double-buffered LDS (2 x 16 KB), one barrier/iter.
// Staging is a linear 8 KB copy per operand tile: each global_load_lds
// instruction moves a contiguous 1 KB (global addr = tile + wave*1024 +
// lane*16 round r*4096; LDS dest = uniform base + lane*16). Bank-swizzle is
// pre-baked by pack_kernel; reader is identical to R5 (verified absmax 0).
__global__ __launch_bounds__(256, 4) void gemm_i8_kernel(
    const signed char* __restrict__ Ap,  // tiled-packed x
    const signed char* __restrict__ Bp,  // tiled-packed w
    const float* __restrict__ sx, const float* __restrict__ sw,
    const float* __restrict__ sy, float* __restrict__ out) {
  __shared__ __align__(16) signed char As[2][TILE_BYTES];
  __shared__ __align__(16) signed char Bs[2][TILE_BYTES];

  const int tid = threadIdx.x;
  const int wave = tid >> 6;
  const int lane = tid & 63;
  const int wm = wave >> 1;  // 0..1: wave row in block
  const int wn = wave & 1;   // 0..1: wave col in block
  const int rowBase = blockIdx.x * BM;   // x-fast over S keeps B L2-resident
  const int colBase = blockIdx.y * BN;

  const int soff = wave * 1024 + lane * 16;  // same offset in tile and LDS
  const signed char* gA = Ap + (size_t)blockIdx.x * NITER * TILE_BYTES + soff;
  const signed char* gB = Bp + (size_t)blockIdx.y * NITER * TILE_BYTES + soff;
  signed char* ldsA = (signed char*)As + wave * 1024;  // + buf*8192 below
  signed char* ldsB = (signed char*)Bs + wave * 1024;

  i32x4 acc[4][4] = {};

  const int fr = lane & 15;                            // fragment row
  const int fq = (((lane >> 4) ^ (fr & 3)) & 3) * 16;  // swizzled chunk slot

  // Prologue: stage tile 0 into buffer 0 (2 contiguous 1 KB pieces per op).
  load_lds16(gA, ldsA);
  load_lds16(gA + 4096, ldsA + 4096);
  load_lds16(gB, ldsB);
  load_lds16(gB + 4096, ldsB + 4096);

  for (int it = 0; it < NITER; ++it) {
    __syncthreads();  // drains vmcnt of stage issued last iter; buffer ready

    if (it + 1 < NITER) {  // async-stage next tile into the other buffer
      const int boff = ((it + 1) & 1) * TILE_BYTES;
      const size_t goff = (size_t)(it + 1) * TILE_BYTES;
      load_lds16(gA + goff, ldsA + boff);
      load_lds16(gA + goff + 4096, ldsA + boff + 4096);
      load_lds16(gB + goff, ldsB + boff);
      load_lds16(gB + goff + 4096, ldsB + boff + 4096);
    }

    const signed char* curA = As[it & 1];
    const signed char* curB = Bs[it & 1];
    i32x4 bf[4];
#pragma unroll
    for (int ni = 0; ni < 4; ++ni)
      bf[ni] = *(const i32x4*)(curB + (wn * 64 + ni * 16 + fr) * BK + fq);

#pragma unroll
    for (int mi = 0; mi < 4; ++mi) {
      i32x4 af = *(const i32x4*)(curA + (wm * 64 + mi * 16 + fr) * BK + fq);
#pragma unroll
      for (int ni = 0; ni < 4; ++ni)
        acc[mi][ni] =
            __builtin_amdgcn_mfma_i32_16x16x64_i8(af, bf[ni], acc[mi][ni], 0, 0, 0);
    }
  }

  // Epilogue. C/D layout: col = lane&15, row = (lane>>4)*4 + reg.
  const float sxw = sx[0] * sw[0];
  const int quad = lane >> 4;
#pragma unroll
  for (int mi = 0; mi < 4; ++mi) {
#pragma unroll
    for (int r = 0; r < 4; ++r) {
      const int s = rowBase + wm * 64 + mi * 16 + quad * 4 + r;
      const float rs = sxw / sy[s];
      float* orow = out + (size_t)s * O_DIM + colBase + wn * 64 + fr;
#pragma unroll
      for (int ni = 0; ni < 4; ++ni) {
        float f = rintf((float)acc[mi][ni][r] * rs);
        f = fminf(127.0f, fmaxf(-128.0f, f));
        orow[ni * 16] = f;
      }
    }
  }
}

extern "C" void kernel_launch(void* const* d_in, const int* in_sizes, int n_in,
                              void* d_out, int out_size, void* d_ws, size_t ws_size,
                              hipStream_t stream) {
  const int* x = (const int*)d_in[0];        // [S,K] int8 values as int32
  const int* w = (const int*)d_in[1];        // [O,K] int8 values as int32
  const float* sx = (const float*)d_in[2];
  const float* sw = (const float*)d_in[3];
  const float* sy = (const float*)d_in[4];   // [S]
  float* out = (float*)d_out;

  uint4* ap = (uint4*)d_ws;                                   // 8 MB tiled A
  uint4* bp = ap + (size_t)S_DIM * K_DIM / 16;                // 4 MB tiled B

  const int total = S_DIM * K_DIM / 16 + O_DIM * K_DIM / 16;  // 768K threads
  pack_kernel<<<(total + 255) / 256, 256, 0, stream>>>(
      x, w, sy, ap, bp, out + (size_t)S_DIM * O_DIM);

  dim3 grid(S_DIM / BM, O_DIM / BN);  // (64, 32), row tiles fast
  gemm_i8_kernel<<<grid, 256, 0, stream>>>(
      (const signed char*)ap, (const signed char*)bp, sx, sw, sy, out);
}